// Round 1
// baseline (348.083 us; speedup 1.0000x reference)
//
#include <hip/hip_runtime.h>
#include <math.h>

#define UDIM 256
#define BATCH 64

__device__ __forceinline__ float softplusf(float x) { return log1pf(expf(x)); }

// ---------------------------------------------------------------------------
// K1: gate pre-activations, activations, mu_out, per-batch scalar reductions.
// One block per batch, 256 threads (one per u).
// scal layout: xx[0..63], pp[64..127], trS[128..191], gg[192..255], trG[256..319]
// ---------------------------------------------------------------------------
__global__ __launch_bounds__(256) void gates_kernel(
    const float* __restrict__ x, const float* __restrict__ prev,
    const float* __restrict__ S,
    const float* __restrict__ Uz, const float* __restrict__ Wz,
    const float* __restrict__ Ur, const float* __restrict__ Wr,
    const float* __restrict__ Uh, const float* __restrict__ Wh,
    float* __restrict__ zb, float* __restrict__ rb, float* __restrict__ hb,
    float* __restrict__ gzb, float* __restrict__ grb, float* __restrict__ ghb,
    float* __restrict__ scal, float* __restrict__ mu_out)
{
  const int b = blockIdx.x;
  const int u = threadIdx.x;
  __shared__ float xs[UDIM], ps[UDIM], gs[UDIM];
  __shared__ float red[256];

  const float xv = x[b*UDIM + u];
  const float pv = prev[b*UDIM + u];
  xs[u] = xv; ps[u] = pv;
  __syncthreads();

  float az = 0.f, ar = 0.f;
  for (int d = 0; d < UDIM; ++d) {
    const float xd = xs[d];
    az = fmaf(xd, Uz[d*UDIM + u], az);
    ar = fmaf(xd, Ur[d*UDIM + u], ar);
  }
  for (int k = 0; k < UDIM; ++k) {
    const float pk = ps[k];
    az = fmaf(pk, Wz[k*UDIM + u], az);
    ar = fmaf(pk, Wr[k*UDIM + u], ar);
  }
  const float zv = 1.f / (1.f + expf(-az));
  const float rv = 1.f / (1.f + expf(-ar));
  const float gv = pv * rv;               // g_in
  gs[u] = gv;
  __syncthreads();

  float ah = 0.f;
  for (int d = 0; d < UDIM; ++d) ah = fmaf(xs[d], Uh[d*UDIM + u], ah);
  for (int k = 0; k < UDIM; ++k) ah = fmaf(gs[k], Wh[k*UDIM + u], ah);
  const float hv = tanhf(ah);

  const int idx = b*UDIM + u;
  zb[idx]  = zv;
  rb[idx]  = rv;
  hb[idx]  = hv;
  gzb[idx] = zv * (1.f - zv);
  grb[idx] = rv * (1.f - rv);
  ghb[idx] = 1.f - hv*hv;
  mu_out[idx] = zv * pv + (1.f - zv) * hv;

  // reductions: xx, pp, trS, gg
  const float diag = S[(size_t)b*UDIM*UDIM + (size_t)u*UDIM + u];
  const float vals[4] = { xv*xv, pv*pv, diag, gv*gv };
#pragma unroll
  for (int q = 0; q < 4; ++q) {
    __syncthreads();
    red[u] = vals[q];
    __syncthreads();
    for (int s = 128; s > 0; s >>= 1) {
      if (u < s) red[u] += red[u + s];
      __syncthreads();
    }
    if (u == 0) scal[q*BATCH + b] = red[0];
  }
  if (u == 0) scal[4*BATCH + b] = 0.f;  // zero trG accumulator
}

// ---------------------------------------------------------------------------
// quad_left: T_b = W^T @ S_b   (T_b(i,j) = sum_k W(k,i) S_b(k,j))
// Tiled fp32 GEMM: BM=BN=64, BK=16, 256 threads, 4x4 micro-tile.
// grid = (U/BN, U/BM, B)
// ---------------------------------------------------------------------------
constexpr int BM = 64, BN = 64, BK = 16;

__global__ __launch_bounds__(256) void quad_left(
    const float* __restrict__ W, const float* __restrict__ S,
    float* __restrict__ T)
{
  const int b  = blockIdx.z;
  const int i0 = blockIdx.y * BM;
  const int j0 = blockIdx.x * BN;
  const float* Sb = S + (size_t)b*UDIM*UDIM;

  __shared__ float As[BK][BM];
  __shared__ float Bs[BK][BN];

  const int t  = threadIdx.x;
  const int tx = t & 15, ty = t >> 4;
  const int lk = t >> 4;         // load row 0..15
  const int lc = (t & 15) * 4;   // load col*4

  float acc[4][4] = {};

  for (int k0 = 0; k0 < UDIM; k0 += BK) {
    const float4 a4 = *(const float4*)(W  + (size_t)(k0+lk)*UDIM + i0 + lc);
    const float4 b4 = *(const float4*)(Sb + (size_t)(k0+lk)*UDIM + j0 + lc);
    __syncthreads();
    *(float4*)&As[lk][lc] = a4;
    *(float4*)&Bs[lk][lc] = b4;
    __syncthreads();
#pragma unroll
    for (int k = 0; k < BK; ++k) {
      const float4 av = *(const float4*)&As[k][ty*4];
      const float4 bv = *(const float4*)&Bs[k][tx*4];
      const float am[4] = {av.x, av.y, av.z, av.w};
      const float bn[4] = {bv.x, bv.y, bv.z, bv.w};
#pragma unroll
      for (int m = 0; m < 4; ++m)
#pragma unroll
        for (int n = 0; n < 4; ++n)
          acc[m][n] = fmaf(am[m], bn[n], acc[m][n]);
    }
  }

  float* Tb = T + (size_t)b*UDIM*UDIM;
#pragma unroll
  for (int m = 0; m < 4; ++m) {
    const float4 o = {acc[m][0], acc[m][1], acc[m][2], acc[m][3]};
    *(float4*)(Tb + (size_t)(i0 + ty*4 + m)*UDIM + j0 + tx*4) = o;
  }
}

// ---------------------------------------------------------------------------
// quad_right<MODE>: Q_b = T_b @ W, fused epilogue.
// MODE 0 (z): out = Sigma_out_z                      (written to d_out sigma)
// MODE 1 (r): out = sigma_g, aux = trG atomics
// MODE 2 (h): out = final Sigma_out; reads Sigma_out_z in-place from `out`
// ---------------------------------------------------------------------------
template<int MODE>
__global__ __launch_bounds__(256) void quad_right(
    const float* __restrict__ T, const float* __restrict__ W,
    const float* __restrict__ S, const float* __restrict__ prev,
    const float* __restrict__ zb, const float* __restrict__ rb,
    const float* __restrict__ hb, const float* __restrict__ gate_g,
    const float* __restrict__ w_sigma, const float* __restrict__ u_sigma,
    const float* __restrict__ scal,
    float* __restrict__ out, float* aux)
{
  const int b  = blockIdx.z;
  const int i0 = blockIdx.y * BM;
  const int j0 = blockIdx.x * BN;
  const float* Tb = T + (size_t)b*UDIM*UDIM;

  __shared__ float As[BK][BM];   // As[k][i] = T_b(i0+i, k0+k)
  __shared__ float Bs[BK][BN];   // Bs[k][j] = W(k0+k, j0+j)

  const int t  = threadIdx.x;
  const int tx = t & 15, ty = t >> 4;
  const int arow = t >> 2;         // 0..63  (i index for A load)
  const int akq  = (t & 3) * 4;    // k quad for A load
  const int lk = t >> 4;
  const int lc = (t & 15) * 4;

  float acc[4][4] = {};

  for (int k0 = 0; k0 < UDIM; k0 += BK) {
    const float4 a4 = *(const float4*)(Tb + (size_t)(i0+arow)*UDIM + k0 + akq);
    const float4 b4 = *(const float4*)(W  + (size_t)(k0+lk)*UDIM + j0 + lc);
    __syncthreads();
    As[akq+0][arow] = a4.x;
    As[akq+1][arow] = a4.y;
    As[akq+2][arow] = a4.z;
    As[akq+3][arow] = a4.w;
    *(float4*)&Bs[lk][lc] = b4;
    __syncthreads();
#pragma unroll
    for (int k = 0; k < BK; ++k) {
      const float4 av = *(const float4*)&As[k][ty*4];
      const float4 bv = *(const float4*)&Bs[k][tx*4];
      const float am[4] = {av.x, av.y, av.z, av.w};
      const float bn[4] = {bv.x, bv.y, bv.z, bv.w};
#pragma unroll
      for (int m = 0; m < 4; ++m)
#pragma unroll
        for (int n = 0; n < 4; ++n)
          acc[m][n] = fmaf(am[m], bn[n], acc[m][n]);
    }
  }

  // ---- epilogue ----
  const float xx  = scal[b];
  const float pp  = scal[BATCH + b];
  const float trS = scal[2*BATCH + b];
  const float gg  = scal[3*BATCH + b];
  const float trG = scal[4*BATCH + b];
  const size_t ob = (size_t)b*UDIM*UDIM;

  float tr_local = 0.f;

#pragma unroll
  for (int m = 0; m < 4; ++m) {
    const int i = i0 + ty*4 + m;
    const float gi = gate_g[b*UDIM + i];
    float pi = 0.f, zi = 0.f, hi = 0.f, ri = 0.f;
    if (MODE >= 1) { pi = prev[b*UDIM + i]; }
    if (MODE == 1) { ri = rb[b*UDIM + i]; }
    if (MODE == 2) { zi = zb[b*UDIM + i]; hi = hb[b*UDIM + i]; }

    float s_[4], sz_[4];
    if (MODE >= 1) {
      const float4 s4 = *(const float4*)(S + ob + (size_t)i*UDIM + j0 + tx*4);
      s_[0]=s4.x; s_[1]=s4.y; s_[2]=s4.z; s_[3]=s4.w;
    }
    if (MODE == 2) {
      const float4 sz4 = *(const float4*)(out + ob + (size_t)i*UDIM + j0 + tx*4);
      sz_[0]=sz4.x; sz_[1]=sz4.y; sz_[2]=sz4.z; sz_[3]=sz4.w;
    }

    float res[4];
#pragma unroll
    for (int n = 0; n < 4; ++n) {
      const int j = j0 + tx*4 + n;
      const float gj = gate_g[b*UDIM + j];
      float q = acc[m][n];
      if (i == j) {
        if (MODE == 2)
          q += (gg + trG) * softplusf(w_sigma[i]) + xx * softplusf(u_sigma[i]);
        else
          q += (pp + trS) * softplusf(w_sigma[i]) + xx * softplusf(u_sigma[i]);
      }
      const float Sg = q * gi * gj;   // Sigma_out_{z|r|h}(i,j)

      if (MODE == 0) {
        res[n] = Sg;
      } else if (MODE == 1) {
        const float pj = prev[b*UDIM + j];
        const float rj = rb[b*UDIM + j];
        const float g  = Sg * (s_[n] + pi*pj) + ri*rj*s_[n];
        res[n] = g;
        if (i == j) tr_local += g;
      } else {
        const float pj = prev[b*UDIM + j];
        const float zj = zb[b*UDIM + j];
        const float hj = hb[b*UDIM + j];
        const float sz = sz_[n];
        float val = s_[n]*(sz + zi*zj)
                  + sz*(pi - hi)*(pj - hj)
                  + Sg*(sz + (1.f - zi)*(1.f - zj));
        if (!isfinite(val)) val = 0.f;
        if (i == j) val = fabsf(val);
        res[n] = val;
      }
    }
    const float4 o = {res[0], res[1], res[2], res[3]};
    *(float4*)(out + ob + (size_t)i*UDIM + j0 + tx*4) = o;
  }

  if (MODE == 1 && i0 == j0 && tx == ty && tr_local != 0.f)
    atomicAdd(&aux[b], tr_local);
}

// ---------------------------------------------------------------------------
extern "C" void kernel_launch(void* const* d_in, const int* in_sizes, int n_in,
                              void* d_out, int out_size, void* d_ws, size_t ws_size,
                              hipStream_t stream) {
  const float* x    = (const float*)d_in[0];
  const float* prev = (const float*)d_in[1];
  const float* S    = (const float*)d_in[2];
  const float* Uz   = (const float*)d_in[3];
  const float* uz_s = (const float*)d_in[4];
  const float* Wz   = (const float*)d_in[5];
  const float* wz_s = (const float*)d_in[6];
  const float* Ur   = (const float*)d_in[7];
  const float* ur_s = (const float*)d_in[8];
  const float* Wr   = (const float*)d_in[9];
  const float* wr_s = (const float*)d_in[10];
  const float* Uh   = (const float*)d_in[11];
  const float* uh_s = (const float*)d_in[12];
  const float* Wh   = (const float*)d_in[13];
  const float* wh_s = (const float*)d_in[14];

  float* out_mu  = (float*)d_out;
  float* out_sig = out_mu + BATCH*UDIM;

  float* ws   = (float*)d_ws;
  float* zb   = ws;
  float* rb   = zb  + BATCH*UDIM;
  float* hb   = rb  + BATCH*UDIM;
  float* gzb  = hb  + BATCH*UDIM;
  float* grb  = gzb + BATCH*UDIM;
  float* ghb  = grb + BATCH*UDIM;
  float* scal = ghb + BATCH*UDIM;              // 320 floats
  float* T    = ws + 131072;                   // [B,U,U]
  float* G    = T + (size_t)BATCH*UDIM*UDIM;   // [B,U,U] sigma_g

  const dim3 blk(256);
  gates_kernel<<<BATCH, blk, 0, stream>>>(x, prev, S, Uz, Wz, Ur, Wr, Uh, Wh,
                                          zb, rb, hb, gzb, grb, ghb, scal, out_mu);

  const dim3 grid(UDIM/BN, UDIM/BM, BATCH);
  // z gate
  quad_left<<<grid, blk, 0, stream>>>(Wz, S, T);
  quad_right<0><<<grid, blk, 0, stream>>>(T, Wz, S, prev, zb, rb, hb, gzb,
                                          wz_s, uz_s, scal, out_sig, nullptr);
  // r gate -> sigma_g
  quad_left<<<grid, blk, 0, stream>>>(Wr, S, T);
  quad_right<1><<<grid, blk, 0, stream>>>(T, Wr, S, prev, zb, rb, hb, grb,
                                          wr_s, ur_s, scal, G, scal + 4*BATCH);
  // h gate + final combine
  quad_left<<<grid, blk, 0, stream>>>(Wh, G, T);
  quad_right<2><<<grid, blk, 0, stream>>>(T, Wh, S, prev, zb, rb, hb, ghb,
                                          wh_s, uh_s, scal, out_sig, nullptr);
}

// Round 3
// 272.404 us; speedup vs baseline: 1.2778x; 1.2778x over previous
//
#include <hip/hip_runtime.h>
#include <math.h>

#define UDIM 256
#define BATCH 64

typedef __bf16 bf16x8 __attribute__((ext_vector_type(8)));
typedef float  f32x4  __attribute__((ext_vector_type(4)));

__device__ __forceinline__ float softplusf(float x) { return log1pf(expf(x)); }

// ---------------------------------------------------------------------------
// transpose3: Wt[i][k] = (__bf16)W[k][i] for the three gate matrices.
// grid (4,4,3), 256 threads, 64x64 tiles.
// ---------------------------------------------------------------------------
__global__ __launch_bounds__(256) void transpose3(
    const float* __restrict__ W0, const float* __restrict__ W1,
    const float* __restrict__ W2,
    __bf16* __restrict__ O0, __bf16* __restrict__ O1, __bf16* __restrict__ O2)
{
  const float* W = blockIdx.z == 0 ? W0 : (blockIdx.z == 1 ? W1 : W2);
  __bf16*      O = blockIdx.z == 0 ? O0 : (blockIdx.z == 1 ? O1 : O2);
  const int k0 = blockIdx.y * 64, i0 = blockIdx.x * 64;
  __shared__ __bf16 tile[64][68];
  const int t = threadIdx.x, tx = t & 15, ty = t >> 4;
#pragma unroll
  for (int rr = 0; rr < 4; ++rr) {
    const int row = ty * 4 + rr;  // k-local
    const float4 f = *(const float4*)(W + (size_t)(k0 + row) * UDIM + i0 + tx * 4);
    tile[row][tx*4+0] = (__bf16)f.x;
    tile[row][tx*4+1] = (__bf16)f.y;
    tile[row][tx*4+2] = (__bf16)f.z;
    tile[row][tx*4+3] = (__bf16)f.w;
  }
  __syncthreads();
#pragma unroll
  for (int rr = 0; rr < 4; ++rr) {
    const int i = ty * 4 + rr;    // i-local
    __align__(8) __bf16 tmp[4];
    tmp[0] = tile[tx*4+0][i];
    tmp[1] = tile[tx*4+1][i];
    tmp[2] = tile[tx*4+2][i];
    tmp[3] = tile[tx*4+3][i];
    *(uint2*)(O + (size_t)(i0 + i) * UDIM + k0 + tx * 4) = *(uint2*)tmp;
  }
}

// ---------------------------------------------------------------------------
// gates1: az, ar -> z, r, gz, gr, g_in.  grid (64,4): batch b, 64-u slice.
// ---------------------------------------------------------------------------
__global__ __launch_bounds__(256) void gates1(
    const float* __restrict__ x, const float* __restrict__ prev,
    const float* __restrict__ Uz, const float* __restrict__ Wz,
    const float* __restrict__ Ur, const float* __restrict__ Wr,
    float* __restrict__ zb, float* __restrict__ rb,
    float* __restrict__ gzb, float* __restrict__ grb, float* __restrict__ gin)
{
  const int b = blockIdx.x, uo = blockIdx.y * 64;
  const int t = threadIdx.x, ul = t & 63, ks = t >> 6;
  __shared__ float xs[UDIM], ps[UDIM], redz[256], redr[256];
  xs[t] = x[b*UDIM + t];
  ps[t] = prev[b*UDIM + t];
  __syncthreads();
  const int u = uo + ul;
  float az = 0.f, ar = 0.f;
  const int k0 = ks * 128;
  if (k0 < 256) {
    for (int kk = k0; kk < k0 + 128; ++kk) {
      const float f = xs[kk];
      az = fmaf(f, Uz[kk*UDIM + u], az);
      ar = fmaf(f, Ur[kk*UDIM + u], ar);
    }
  } else {
    for (int kk = k0 - 256; kk < k0 - 128; ++kk) {
      const float f = ps[kk];
      az = fmaf(f, Wz[kk*UDIM + u], az);
      ar = fmaf(f, Wr[kk*UDIM + u], ar);
    }
  }
  redz[t] = az; redr[t] = ar;
  __syncthreads();
  if (t < 64) {
    az = redz[t] + redz[t+64] + redz[t+128] + redz[t+192];
    ar = redr[t] + redr[t+64] + redr[t+128] + redr[t+192];
    const float zv = 1.f / (1.f + expf(-az));
    const float rv = 1.f / (1.f + expf(-ar));
    const int idx = b*UDIM + uo + t;
    zb[idx]  = zv;
    rb[idx]  = rv;
    gzb[idx] = zv * (1.f - zv);
    grb[idx] = rv * (1.f - rv);
    gin[idx] = ps[uo + t] * rv;
  }
}

// ---------------------------------------------------------------------------
// gates2: ah -> h, gh, mu_out + scalar reductions (xx, pp, trS, gg) atomics.
// ---------------------------------------------------------------------------
__global__ __launch_bounds__(256) void gates2(
    const float* __restrict__ x, const float* __restrict__ prev,
    const float* __restrict__ S,
    const float* __restrict__ Uh, const float* __restrict__ Wh,
    const float* __restrict__ gin, const float* __restrict__ zb,
    float* __restrict__ hb, float* __restrict__ ghb,
    float* __restrict__ mu_out, float* __restrict__ scal)
{
  const int b = blockIdx.x, uo = blockIdx.y * 64;
  const int t = threadIdx.x, ul = t & 63, ks = t >> 6;
  __shared__ float xs[UDIM], ps[UDIM], gs[UDIM], red[256];
  xs[t] = x[b*UDIM + t];
  ps[t] = prev[b*UDIM + t];
  gs[t] = gin[b*UDIM + t];
  __syncthreads();
  const int u = uo + ul;
  float ah = 0.f;
  const int k0 = ks * 128;
  if (k0 < 256) {
    for (int kk = k0; kk < k0 + 128; ++kk)
      ah = fmaf(xs[kk], Uh[kk*UDIM + u], ah);
  } else {
    for (int kk = k0 - 256; kk < k0 - 128; ++kk)
      ah = fmaf(gs[kk], Wh[kk*UDIM + u], ah);
  }
  red[t] = ah;
  __syncthreads();
  if (t < 64) {
    ah = red[t] + red[t+64] + red[t+128] + red[t+192];
    const float hv = tanhf(ah);
    const int idx = b*UDIM + uo + t;
    hb[idx]  = hv;
    ghb[idx] = 1.f - hv*hv;
    mu_out[idx] = zb[idx] * ps[uo+t] + (1.f - zb[idx]) * hv;
    const float xv = xs[uo+t], pv = ps[uo+t], gv = gs[uo+t];
    float v0 = xv*xv, v1 = pv*pv;
    float v2 = S[(size_t)b*UDIM*UDIM + (size_t)(uo+t)*UDIM + (uo+t)];
    float v3 = gv*gv;
    for (int off = 32; off > 0; off >>= 1) {
      v0 += __shfl_down(v0, off);
      v1 += __shfl_down(v1, off);
      v2 += __shfl_down(v2, off);
      v3 += __shfl_down(v3, off);
    }
    if (t == 0) {
      atomicAdd(&scal[b],       v0);
      atomicAdd(&scal[64 + b],  v1);
      atomicAdd(&scal[128 + b], v2);
      atomicAdd(&scal[192 + b], v3);
    }
  }
}

// ---------------------------------------------------------------------------
// MFMA GEMM tiles: BM=128, BN=64, BK=32, 256 threads (4 waves).
// A is [i][k] bf16, B source is [j][k] (symmetric matrix rows or Wt rows).
// C(i,j) = sum_k A[i][k]*B[j][k].
// ---------------------------------------------------------------------------
constexpr int QBM = 128, QBN = 64, QBK = 32, QLD = 40;

// quad_left_mfma<BF32>: T_b = Wt @ S_b  (S symmetric: rows are B fragments)
template<bool BF32>
__global__ __launch_bounds__(256) void quad_left_mfma(
    const __bf16* __restrict__ Wt,       // [U][U] bf16 A operand (shared by batches)
    const float* __restrict__ Bf,        // [B,U,U] fp32 (S)  if BF32
    const __bf16* __restrict__ Bb,       // [B,U,U] bf16 (G)  if !BF32
    __bf16* __restrict__ Tout)           // [B,U,U] bf16
{
  const int b  = blockIdx.z;
  const int i0 = blockIdx.y * QBM;
  const int j0 = blockIdx.x * QBN;
  const long bofs = (long)b * UDIM * UDIM;

  __shared__ __align__(16) __bf16 As[QBM][QLD];
  __shared__ __align__(16) __bf16 Bs[QBN][QLD];

  const int t = threadIdx.x;
  const int l = t & 63, w = t >> 6;
  const int r = l & 15, q = l >> 4;

  f32x4 acc[2][4] = {};

  for (int k0 = 0; k0 < UDIM; k0 += QBK) {
    const int arow = t >> 1, aseg = t & 1;
    const uint4* asrc = (const uint4*)(Wt + (size_t)(i0 + arow) * UDIM + k0 + aseg*16);
    const uint4 a0 = asrc[0], a1 = asrc[1];

    const int brow = t >> 2, bq = t & 3;
    uint4 bregs;
    if constexpr (BF32) {
      const float* bsrc = Bf + bofs + (size_t)(j0 + brow) * UDIM + k0 + bq*8;
      const float4 f0 = *(const float4*)bsrc;
      const float4 f1 = *(const float4*)(bsrc + 4);
      __align__(16) __bf16 tmp[8];
      tmp[0]=(__bf16)f0.x; tmp[1]=(__bf16)f0.y; tmp[2]=(__bf16)f0.z; tmp[3]=(__bf16)f0.w;
      tmp[4]=(__bf16)f1.x; tmp[5]=(__bf16)f1.y; tmp[6]=(__bf16)f1.z; tmp[7]=(__bf16)f1.w;
      bregs = *(const uint4*)tmp;
    } else {
      bregs = *(const uint4*)(Bb + bofs + (size_t)(j0 + brow) * UDIM + k0 + bq*8);
    }

    __syncthreads();
    *(uint4*)&As[arow][aseg*16]     = a0;
    *(uint4*)&As[arow][aseg*16 + 8] = a1;
    *(uint4*)&Bs[brow][bq*8]        = bregs;
    __syncthreads();

    bf16x8 af[2], bv[4];
#pragma unroll
    for (int mi = 0; mi < 2; ++mi)
      af[mi] = *(const bf16x8*)&As[w*32 + mi*16 + r][q*8];
#pragma unroll
    for (int ni = 0; ni < 4; ++ni)
      bv[ni] = *(const bf16x8*)&Bs[ni*16 + r][q*8];
#pragma unroll
    for (int mi = 0; mi < 2; ++mi)
#pragma unroll
      for (int ni = 0; ni < 4; ++ni)
        acc[mi][ni] = __builtin_amdgcn_mfma_f32_16x16x32_bf16(
            af[mi], bv[ni], acc[mi][ni], 0, 0, 0);
  }

  __bf16* To = Tout + bofs;
#pragma unroll
  for (int mi = 0; mi < 2; ++mi)
#pragma unroll
    for (int ni = 0; ni < 4; ++ni)
#pragma unroll
      for (int v = 0; v < 4; ++v)
        To[(size_t)(i0 + w*32 + mi*16 + q*4 + v) * UDIM + j0 + ni*16 + r]
            = (__bf16)acc[mi][ni][v];
}

// quad_right_mfma<MODE>: Q_b = T_b @ W  (B operand = Wt rows [j][k]); epilogue:
// MODE 0: Sigma_out_z -> out_sig
// MODE 1: sigma_g -> Gout (bf16) + trG atomics into scal[256+b]
// MODE 2: final Sigma_out -> out_sig (reads Sz in-place)
template<int MODE>
__global__ __launch_bounds__(256) void quad_right_mfma(
    const __bf16* __restrict__ T,        // [B,U,U] bf16, A operand
    const __bf16* __restrict__ Wt,       // [U][U] bf16, B operand
    const float* __restrict__ S,
    const float* __restrict__ prev,
    const float* __restrict__ zb, const float* __restrict__ rb,
    const float* __restrict__ hb, const float* __restrict__ gate_g,
    const float* __restrict__ w_sigma, const float* __restrict__ u_sigma,
    float* __restrict__ scal,
    float* __restrict__ out_sig, __bf16* __restrict__ Gout)
{
  const int b  = blockIdx.z;
  const int i0 = blockIdx.y * QBM;
  const int j0 = blockIdx.x * QBN;
  const long ob = (long)b * UDIM * UDIM;
  const __bf16* A = T + ob;

  __shared__ __align__(16) __bf16 As[QBM][QLD];
  __shared__ __align__(16) __bf16 Bs[QBN][QLD];

  const int t = threadIdx.x;
  const int l = t & 63, w = t >> 6;
  const int r = l & 15, q = l >> 4;

  f32x4 acc[2][4] = {};

  for (int k0 = 0; k0 < UDIM; k0 += QBK) {
    const int arow = t >> 1, aseg = t & 1;
    const uint4* asrc = (const uint4*)(A + (size_t)(i0 + arow) * UDIM + k0 + aseg*16);
    const uint4 a0 = asrc[0], a1 = asrc[1];

    const int brow = t >> 2, bq = t & 3;
    const uint4 bregs = *(const uint4*)(Wt + (size_t)(j0 + brow) * UDIM + k0 + bq*8);

    __syncthreads();
    *(uint4*)&As[arow][aseg*16]     = a0;
    *(uint4*)&As[arow][aseg*16 + 8] = a1;
    *(uint4*)&Bs[brow][bq*8]        = bregs;
    __syncthreads();

    bf16x8 af[2], bv[4];
#pragma unroll
    for (int mi = 0; mi < 2; ++mi)
      af[mi] = *(const bf16x8*)&As[w*32 + mi*16 + r][q*8];
#pragma unroll
    for (int ni = 0; ni < 4; ++ni)
      bv[ni] = *(const bf16x8*)&Bs[ni*16 + r][q*8];
#pragma unroll
    for (int mi = 0; mi < 2; ++mi)
#pragma unroll
      for (int ni = 0; ni < 4; ++ni)
        acc[mi][ni] = __builtin_amdgcn_mfma_f32_16x16x32_bf16(
            af[mi], bv[ni], acc[mi][ni], 0, 0, 0);
  }

  const float xx  = scal[b];
  const float pp  = scal[64 + b];
  const float trS = scal[128 + b];
  const float gg  = scal[192 + b];
  const float trG = (MODE == 2) ? scal[256 + b] : 0.f;
  const float dscal = (MODE == 2) ? (gg + trG) : (pp + trS);

#pragma unroll
  for (int mi = 0; mi < 2; ++mi) {
    const int ib = i0 + w*32 + mi*16 + q*4;
    const f32x4 g4 = *(const f32x4*)(gate_g + b*UDIM + ib);
    f32x4 p4{}, z4{}, h4{}, r4{};
    if constexpr (MODE >= 1) p4 = *(const f32x4*)(prev + b*UDIM + ib);
    if constexpr (MODE == 1) r4 = *(const f32x4*)(rb + b*UDIM + ib);
    if constexpr (MODE == 2) {
      z4 = *(const f32x4*)(zb + b*UDIM + ib);
      h4 = *(const f32x4*)(hb + b*UDIM + ib);
    }
#pragma unroll
    for (int ni = 0; ni < 4; ++ni) {
      const int j = j0 + ni*16 + r;
      const float gj = gate_g[b*UDIM + j];
      float pj = 0.f, rj = 0.f, zj = 0.f, hj = 0.f;
      if constexpr (MODE >= 1) pj = prev[b*UDIM + j];
      if constexpr (MODE == 1) rj = rb[b*UDIM + j];
      if constexpr (MODE == 2) { zj = zb[b*UDIM + j]; hj = hb[b*UDIM + j]; }
#pragma unroll
      for (int v = 0; v < 4; ++v) {
        const int i = ib + v;
        float qv = acc[mi][ni][v];
        if (i == j)
          qv += dscal * softplusf(w_sigma[i]) + xx * softplusf(u_sigma[i]);
        const float Sg = qv * g4[v] * gj;
        if constexpr (MODE == 0) {
          out_sig[ob + (size_t)i*UDIM + j] = Sg;
        } else if constexpr (MODE == 1) {
          const float s = S[ob + (size_t)i*UDIM + j];
          const float go = Sg * (s + p4[v]*pj) + r4[v]*rj*s;
          Gout[ob + (size_t)i*UDIM + j] = (__bf16)go;
          if (i == j) atomicAdd(&scal[256 + b], go);
        } else {
          const float s  = S[ob + (size_t)i*UDIM + j];
          const float sz = out_sig[ob + (size_t)i*UDIM + j];
          float val = s * (sz + z4[v]*zj)
                    + sz * (p4[v]-h4[v]) * (pj-hj)
                    + Sg * (sz + (1.f-z4[v])*(1.f-zj));
          if (!isfinite(val)) val = 0.f;
          if (i == j) val = fabsf(val);
          out_sig[ob + (size_t)i*UDIM + j] = val;
        }
      }
    }
  }
}

// ---------------------------------------------------------------------------
extern "C" void kernel_launch(void* const* d_in, const int* in_sizes, int n_in,
                              void* d_out, int out_size, void* d_ws, size_t ws_size,
                              hipStream_t stream) {
  const float* x    = (const float*)d_in[0];
  const float* prev = (const float*)d_in[1];
  const float* S    = (const float*)d_in[2];
  const float* Uz   = (const float*)d_in[3];
  const float* uz_s = (const float*)d_in[4];
  const float* Wz   = (const float*)d_in[5];
  const float* wz_s = (const float*)d_in[6];
  const float* Ur   = (const float*)d_in[7];
  const float* ur_s = (const float*)d_in[8];
  const float* Wr   = (const float*)d_in[9];
  const float* wr_s = (const float*)d_in[10];
  const float* Uh   = (const float*)d_in[11];
  const float* uh_s = (const float*)d_in[12];
  const float* Wh   = (const float*)d_in[13];
  const float* wh_s = (const float*)d_in[14];

  float* out_mu  = (float*)d_out;
  float* out_sig = out_mu + BATCH*UDIM;

  float* ws   = (float*)d_ws;
  float* zb   = ws;
  float* rb   = zb  + BATCH*UDIM;
  float* gzb  = rb  + BATCH*UDIM;
  float* grb  = gzb + BATCH*UDIM;
  float* gin  = grb + BATCH*UDIM;
  float* hb   = gin + BATCH*UDIM;
  float* ghb  = hb  + BATCH*UDIM;
  float* scal = ghb + BATCH*UDIM;            // 512 floats
  __bf16* bws = (__bf16*)(ws + 7*BATCH*UDIM + 512);
  __bf16* Wtz = bws;
  __bf16* Wtr = Wtz + UDIM*UDIM;
  __bf16* Wth = Wtr + UDIM*UDIM;
  __bf16* T   = Wth + UDIM*UDIM;             // [B,U,U] bf16
  __bf16* G   = T + (size_t)BATCH*UDIM*UDIM; // [B,U,U] bf16

  hipMemsetAsync(scal, 0, 512 * sizeof(float), stream);

  transpose3<<<dim3(4,4,3), 256, 0, stream>>>(Wz, Wr, Wh, Wtz, Wtr, Wth);
  gates1<<<dim3(BATCH,4), 256, 0, stream>>>(x, prev, Uz, Wz, Ur, Wr,
                                            zb, rb, gzb, grb, gin);
  gates2<<<dim3(BATCH,4), 256, 0, stream>>>(x, prev, S, Uh, Wh, gin, zb,
                                            hb, ghb, out_mu, scal);

  const dim3 qg(UDIM/QBN, UDIM/QBM, BATCH);  // (4, 2, 64)

  // z gate
  quad_left_mfma<true ><<<qg,256,0,stream>>>(Wtz, S, nullptr, T);
  quad_right_mfma<0><<<qg,256,0,stream>>>(T, Wtz, nullptr, nullptr, nullptr,
      nullptr, nullptr, gzb, wz_s, uz_s, scal, out_sig, nullptr);
  // r gate -> sigma_g (bf16) + trG
  quad_left_mfma<true ><<<qg,256,0,stream>>>(Wtr, S, nullptr, T);
  quad_right_mfma<1><<<qg,256,0,stream>>>(T, Wtr, S, prev, nullptr,
      rb, nullptr, grb, wr_s, ur_s, scal, nullptr, G);
  // h gate + final combine
  quad_left_mfma<false><<<qg,256,0,stream>>>(Wth, nullptr, G, T);
  quad_right_mfma<2><<<qg,256,0,stream>>>(T, Wth, S, prev, zb,
      nullptr, hb, ghb, wh_s, uh_s, scal, out_sig, nullptr);
}

// Round 4
// 226.113 us; speedup vs baseline: 1.5394x; 1.2047x over previous
//
#include <hip/hip_runtime.h>
#include <math.h>

#define UDIM 256
#define BATCH 64

typedef __bf16 bf16x8 __attribute__((ext_vector_type(8)));
typedef float  f32x4  __attribute__((ext_vector_type(4)));

__device__ __forceinline__ float softplusf(float x) { return log1pf(expf(x)); }
__device__ __forceinline__ float sigmoidf_(float x) { return 1.f/(1.f+expf(-x)); }

// ---------------------------------------------------------------------------
// transpose6: Ot[n][k] = (__bf16)W[k][n] for all 6 weight matrices.
// grid (4,4,6), 256 threads, 64x64 tiles.
// ---------------------------------------------------------------------------
__global__ __launch_bounds__(256) void transpose6(
    const float* __restrict__ W0, const float* __restrict__ W1,
    const float* __restrict__ W2, const float* __restrict__ W3,
    const float* __restrict__ W4, const float* __restrict__ W5,
    __bf16* __restrict__ O0, __bf16* __restrict__ O1, __bf16* __restrict__ O2,
    __bf16* __restrict__ O3, __bf16* __restrict__ O4, __bf16* __restrict__ O5)
{
  const float* W; __bf16* O;
  switch (blockIdx.z) {
    case 0: W=W0; O=O0; break;  case 1: W=W1; O=O1; break;
    case 2: W=W2; O=O2; break;  case 3: W=W3; O=O3; break;
    case 4: W=W4; O=O4; break;  default: W=W5; O=O5; break;
  }
  const int k0 = blockIdx.y * 64, i0 = blockIdx.x * 64;
  __shared__ __bf16 tile[64][68];
  const int t = threadIdx.x, tx = t & 15, ty = t >> 4;
#pragma unroll
  for (int rr = 0; rr < 4; ++rr) {
    const int row = ty * 4 + rr;  // k-local
    const float4 f = *(const float4*)(W + (size_t)(k0 + row) * UDIM + i0 + tx * 4);
    tile[row][tx*4+0] = (__bf16)f.x;
    tile[row][tx*4+1] = (__bf16)f.y;
    tile[row][tx*4+2] = (__bf16)f.z;
    tile[row][tx*4+3] = (__bf16)f.w;
  }
  __syncthreads();
#pragma unroll
  for (int rr = 0; rr < 4; ++rr) {
    const int i = ty * 4 + rr;    // n-local
    __align__(8) __bf16 tmp[4];
    tmp[0] = tile[tx*4+0][i];
    tmp[1] = tile[tx*4+1][i];
    tmp[2] = tile[tx*4+2][i];
    tmp[3] = tile[tx*4+3][i];
    *(uint2*)(O + (size_t)(i0 + i) * UDIM + k0 + tx * 4) = *(uint2*)tmp;
  }
}

// ---------------------------------------------------------------------------
// sconv: S -> bf16 copy + scalar reductions trS (all blocks), xx, pp (rg==0).
// grid (64, 4): batch b, 64-row group.
// scal: xx[0..63], pp[64..127], trS[128..191], gg[192..255], trG[256..319]
// ---------------------------------------------------------------------------
__global__ __launch_bounds__(256) void sconv(
    const float* __restrict__ S, const float* __restrict__ x,
    const float* __restrict__ prev,
    __bf16* __restrict__ Sbf, float* __restrict__ scal)
{
  const int b = blockIdx.x, rg = blockIdx.y;
  const size_t base = (size_t)b*UDIM*UDIM + (size_t)rg*64*UDIM;
  const int t = threadIdx.x;
#pragma unroll
  for (int e = 0; e < 16; ++e) {
    const size_t f = (size_t)e*256 + t;
    const float4 v = *(const float4*)(S + base + f*4);
    __align__(8) __bf16 tmp[4] = {(__bf16)v.x,(__bf16)v.y,(__bf16)v.z,(__bf16)v.w};
    *(uint2*)(Sbf + base + f*4) = *(const uint2*)tmp;
  }
  const int wv = t >> 6, l = t & 63;
  if (wv == 0) {
    const int i = rg*64 + l;
    float v = S[(size_t)b*UDIM*UDIM + (size_t)i*UDIM + i];
    for (int s = 32; s > 0; s >>= 1) v += __shfl_down(v, s);
    if (l == 0) atomicAdd(&scal[128 + b], v);
  } else if (wv == 1 && rg == 0) {
    const float4 v = *(const float4*)(x + b*UDIM + l*4);
    float s2 = v.x*v.x + v.y*v.y + v.z*v.z + v.w*v.w;
    for (int s = 32; s > 0; s >>= 1) s2 += __shfl_down(s2, s);
    if (l == 0) atomicAdd(&scal[b], s2);
  } else if (wv == 2 && rg == 0) {
    const float4 v = *(const float4*)(prev + b*UDIM + l*4);
    float s2 = v.x*v.x + v.y*v.y + v.z*v.z + v.w*v.w;
    for (int s = 32; s > 0; s >>= 1) s2 += __shfl_down(s2, s);
    if (l == 0) atomicAdd(&scal[64 + b], s2);
  }
}

// ---------------------------------------------------------------------------
// gates_zr: az/ar = x@U + prev@W via MFMA straight from global (no LDS).
// grid (4 j-tiles, 2 gates), 256 threads = 4 waves; wave w handles batch rows
// w*16..w*16+15, all 64 cols of its j-tile.  M=64(batch), N=64, K=512.
// gate 0 -> z, gz ; gate 1 -> r, gr, gin, gg atomics.
// ---------------------------------------------------------------------------
__global__ __launch_bounds__(256) void gates_zr(
    const float* __restrict__ x, const float* __restrict__ prev,
    const __bf16* __restrict__ Utz, const __bf16* __restrict__ Wtz,
    const __bf16* __restrict__ Utr, const __bf16* __restrict__ Wtr,
    float* __restrict__ zb, float* __restrict__ rb,
    float* __restrict__ gzb, float* __restrict__ grb,
    float* __restrict__ gin, float* __restrict__ scal)
{
  const int j0 = blockIdx.x * 64;
  const int gate = blockIdx.y;
  const __bf16* Umat = gate ? Utr : Utz;
  const __bf16* Wmat = gate ? Wtr : Wtz;
  const int t = threadIdx.x, w = t >> 6, l = t & 63, r = l & 15, q = l >> 4;
  const int mrow = w*16 + r;

  f32x4 acc[4] = {};
#pragma unroll
  for (int ks = 0; ks < 16; ++ks) {
    const int k0 = ks * 32;
    const float* asrc;
    const __bf16* B;
    int kk;
    if (k0 < 256) { asrc = x    + (size_t)mrow*UDIM + k0       + q*8; B = Umat; kk = k0; }
    else          { asrc = prev + (size_t)mrow*UDIM + (k0-256) + q*8; B = Wmat; kk = k0-256; }
    const float4 f0 = *(const float4*)asrc;
    const float4 f1 = *(const float4*)(asrc + 4);
    bf16x8 af;
    af[0]=(__bf16)f0.x; af[1]=(__bf16)f0.y; af[2]=(__bf16)f0.z; af[3]=(__bf16)f0.w;
    af[4]=(__bf16)f1.x; af[5]=(__bf16)f1.y; af[6]=(__bf16)f1.z; af[7]=(__bf16)f1.w;
#pragma unroll
    for (int ni = 0; ni < 4; ++ni) {
      const bf16x8 bv = *(const bf16x8*)(B + (size_t)(j0 + ni*16 + r)*UDIM + kk + q*8);
      acc[ni] = __builtin_amdgcn_mfma_f32_16x16x32_bf16(af, bv, acc[ni], 0, 0, 0);
    }
  }

  if (gate == 0) {
#pragma unroll
    for (int ni = 0; ni < 4; ++ni) {
      const int n = j0 + ni*16 + r;
#pragma unroll
      for (int v = 0; v < 4; ++v) {
        const int m = w*16 + q*4 + v;
        const float zv = sigmoidf_(acc[ni][v]);
        zb[m*UDIM + n]  = zv;
        gzb[m*UDIM + n] = zv * (1.f - zv);
      }
    }
  } else {
    float ggp[4] = {0.f, 0.f, 0.f, 0.f};
#pragma unroll
    for (int ni = 0; ni < 4; ++ni) {
      const int n = j0 + ni*16 + r;
#pragma unroll
      for (int v = 0; v < 4; ++v) {
        const int m = w*16 + q*4 + v;
        const float rv = sigmoidf_(acc[ni][v]);
        const float pv = prev[m*UDIM + n];
        const float g  = pv * rv;
        rb[m*UDIM + n]  = rv;
        grb[m*UDIM + n] = rv * (1.f - rv);
        gin[m*UDIM + n] = g;
        ggp[v] += g * g;
      }
    }
#pragma unroll
    for (int s = 1; s < 16; s <<= 1)
#pragma unroll
      for (int v = 0; v < 4; ++v) ggp[v] += __shfl_xor(ggp[v], s);
    if (r == 0)
#pragma unroll
      for (int v = 0; v < 4; ++v)
        atomicAdd(&scal[192 + w*16 + q*4 + v], ggp[v]);
  }
}

// ---------------------------------------------------------------------------
// gates_h: ah = x@Uh + gin@Wh -> h, gh, mu_out. grid (4), same MFMA scheme.
// ---------------------------------------------------------------------------
__global__ __launch_bounds__(256) void gates_h(
    const float* __restrict__ x, const float* __restrict__ gin,
    const __bf16* __restrict__ Uth, const __bf16* __restrict__ Wth,
    const float* __restrict__ prev, const float* __restrict__ zb,
    float* __restrict__ hb, float* __restrict__ ghb, float* __restrict__ mu_out)
{
  const int j0 = blockIdx.x * 64;
  const int t = threadIdx.x, w = t >> 6, l = t & 63, r = l & 15, q = l >> 4;
  const int mrow = w*16 + r;

  f32x4 acc[4] = {};
#pragma unroll
  for (int ks = 0; ks < 16; ++ks) {
    const int k0 = ks * 32;
    const float* asrc;
    const __bf16* B;
    int kk;
    if (k0 < 256) { asrc = x   + (size_t)mrow*UDIM + k0       + q*8; B = Uth; kk = k0; }
    else          { asrc = gin + (size_t)mrow*UDIM + (k0-256) + q*8; B = Wth; kk = k0-256; }
    const float4 f0 = *(const float4*)asrc;
    const float4 f1 = *(const float4*)(asrc + 4);
    bf16x8 af;
    af[0]=(__bf16)f0.x; af[1]=(__bf16)f0.y; af[2]=(__bf16)f0.z; af[3]=(__bf16)f0.w;
    af[4]=(__bf16)f1.x; af[5]=(__bf16)f1.y; af[6]=(__bf16)f1.z; af[7]=(__bf16)f1.w;
#pragma unroll
    for (int ni = 0; ni < 4; ++ni) {
      const bf16x8 bv = *(const bf16x8*)(B + (size_t)(j0 + ni*16 + r)*UDIM + kk + q*8);
      acc[ni] = __builtin_amdgcn_mfma_f32_16x16x32_bf16(af, bv, acc[ni], 0, 0, 0);
    }
  }

#pragma unroll
  for (int ni = 0; ni < 4; ++ni) {
    const int n = j0 + ni*16 + r;
#pragma unroll
    for (int v = 0; v < 4; ++v) {
      const int m = w*16 + q*4 + v;
      const float hv = tanhf(acc[ni][v]);
      const float zv = zb[m*UDIM + n];
      hb[m*UDIM + n]  = hv;
      ghb[m*UDIM + n] = 1.f - hv*hv;
      mu_out[m*UDIM + n] = zv * prev[m*UDIM + n] + (1.f - zv) * hv;
    }
  }
}

// ---------------------------------------------------------------------------
// Quad-form GEMM tiles: BM=128, BN=64, BK=32, 256 threads, register prefetch.
// C(i,j) = sum_k A[i][k] * B[j][k].
// ---------------------------------------------------------------------------
constexpr int QBM = 128, QBN = 64, QBK = 32, QLD = 40;

#define QGEMM_CORE(APTR, BPTR)                                                 \
  __shared__ __align__(16) __bf16 As[QBM][QLD];                                \
  __shared__ __align__(16) __bf16 Bs[QBN][QLD];                                \
  const int t = threadIdx.x, l = t & 63, w = t >> 6, r = l & 15, q = l >> 4;   \
  const int arow = t >> 1, aseg = t & 1, brow = t >> 2, bq = t & 3;            \
  uint4 a0, a1, b0;                                                            \
  {                                                                            \
    const uint4* ap = (const uint4*)((APTR) + (size_t)(i0+arow)*UDIM + aseg*16);\
    a0 = ap[0]; a1 = ap[1];                                                    \
    b0 = *(const uint4*)((BPTR) + (size_t)(j0+brow)*UDIM + bq*8);              \
  }                                                                            \
  f32x4 acc[2][4] = {};                                                        \
  for (int k0 = 0; k0 < UDIM; k0 += QBK) {                                     \
    __syncthreads();                                                           \
    *(uint4*)&As[arow][aseg*16]     = a0;                                      \
    *(uint4*)&As[arow][aseg*16 + 8] = a1;                                      \
    *(uint4*)&Bs[brow][bq*8]        = b0;                                      \
    __syncthreads();                                                           \
    if (k0 + QBK < UDIM) {                                                     \
      const uint4* ap = (const uint4*)((APTR) + (size_t)(i0+arow)*UDIM + k0+QBK + aseg*16);\
      a0 = ap[0]; a1 = ap[1];                                                  \
      b0 = *(const uint4*)((BPTR) + (size_t)(j0+brow)*UDIM + k0+QBK + bq*8);   \
    }                                                                          \
    bf16x8 af[2], bv[4];                                                       \
    _Pragma("unroll")                                                          \
    for (int mi = 0; mi < 2; ++mi)                                             \
      af[mi] = *(const bf16x8*)&As[w*32 + mi*16 + r][q*8];                     \
    _Pragma("unroll")                                                          \
    for (int ni = 0; ni < 4; ++ni)                                             \
      bv[ni] = *(const bf16x8*)&Bs[ni*16 + r][q*8];                            \
    _Pragma("unroll")                                                          \
    for (int mi = 0; mi < 2; ++mi)                                             \
      _Pragma("unroll")                                                        \
      for (int ni = 0; ni < 4; ++ni)                                           \
        acc[mi][ni] = __builtin_amdgcn_mfma_f32_16x16x32_bf16(                 \
            af[mi], bv[ni], acc[mi][ni], 0, 0, 0);                             \
  }

// left_zr: T_g = Wt_g @ S_b  (g in {z,r}).  grid (4, 2, 128): z = b + 64*gate.
__global__ __launch_bounds__(256) void left_zr(
    const __bf16* __restrict__ Wtz, const __bf16* __restrict__ Wtr,
    const __bf16* __restrict__ Sbf,
    __bf16* __restrict__ Tz, __bf16* __restrict__ Tr)
{
  const int gate = blockIdx.z >> 6, b = blockIdx.z & 63;
  const int i0 = blockIdx.y * QBM, j0 = blockIdx.x * QBN;
  const long bofs = (long)b * UDIM * UDIM;
  const __bf16* A = gate ? Wtr : Wtz;
  const __bf16* B = Sbf + bofs;
  __bf16* Out = (gate ? Tr : Tz) + bofs;

  QGEMM_CORE(A, B)

#pragma unroll
  for (int mi = 0; mi < 2; ++mi)
#pragma unroll
    for (int ni = 0; ni < 4; ++ni)
#pragma unroll
      for (int v = 0; v < 4; ++v)
        Out[(size_t)(i0 + w*32 + mi*16 + q*4 + v)*UDIM + j0 + ni*16 + r]
            = (__bf16)acc[mi][ni][v];
}

// right_zr: Q = T_g @ W_g + diag; gate0 -> Sigma_out_z (fp32 to out_sig);
// gate1 -> sigma_g (bf16 G) + trG atomics.
__global__ __launch_bounds__(256) void right_zr(
    const __bf16* __restrict__ Tz, const __bf16* __restrict__ Tr,
    const __bf16* __restrict__ Wtz, const __bf16* __restrict__ Wtr,
    const float* __restrict__ S, const float* __restrict__ prev,
    const float* __restrict__ rb,
    const float* __restrict__ gzb, const float* __restrict__ grb,
    const float* __restrict__ wz_s, const float* __restrict__ uz_s,
    const float* __restrict__ wr_s, const float* __restrict__ ur_s,
    float* __restrict__ scal, float* __restrict__ out_sig,
    __bf16* __restrict__ G)
{
  const int gate = blockIdx.z >> 6, b = blockIdx.z & 63;
  const int i0 = blockIdx.y * QBM, j0 = blockIdx.x * QBN;
  const long ob = (long)b * UDIM * UDIM;
  const __bf16* A = (gate ? Tr : Tz) + ob;
  const __bf16* B = gate ? Wtr : Wtz;

  QGEMM_CORE(A, B)

  const float xx = scal[b];
  const float dscal = scal[64 + b] + scal[128 + b];   // pp + trS
  const float* gate_g = gate ? grb : gzb;
  const float* ws_ = gate ? wr_s : wz_s;
  const float* us_ = gate ? ur_s : uz_s;

#pragma unroll
  for (int mi = 0; mi < 2; ++mi) {
    const int ib = i0 + w*32 + mi*16 + q*4;
    const f32x4 g4 = *(const f32x4*)(gate_g + b*UDIM + ib);
    f32x4 p4{}, r4{};
    if (gate) {
      p4 = *(const f32x4*)(prev + b*UDIM + ib);
      r4 = *(const f32x4*)(rb + b*UDIM + ib);
    }
#pragma unroll
    for (int ni = 0; ni < 4; ++ni) {
      const int j = j0 + ni*16 + r;
      const float gj = gate_g[b*UDIM + j];
      float pj = 0.f, rj = 0.f;
      if (gate) { pj = prev[b*UDIM + j]; rj = rb[b*UDIM + j]; }
#pragma unroll
      for (int v = 0; v < 4; ++v) {
        const int i = ib + v;
        float qv = acc[mi][ni][v];
        if (i == j)
          qv += dscal * softplusf(ws_[i]) + xx * softplusf(us_[i]);
        const float Sg = qv * g4[v] * gj;
        if (!gate) {
          out_sig[ob + (size_t)i*UDIM + j] = Sg;
        } else {
          const float s = S[ob + (size_t)i*UDIM + j];
          const float go = Sg * (s + p4[v]*pj) + r4[v]*rj*s;
          G[ob + (size_t)i*UDIM + j] = (__bf16)go;
          if (i == j) atomicAdd(&scal[256 + b], go);
        }
      }
    }
  }
}

// left_h: T_h = Wt_h @ sigma_g.  grid (4, 2, 64).
__global__ __launch_bounds__(256) void left_h(
    const __bf16* __restrict__ Wth, const __bf16* __restrict__ G,
    __bf16* __restrict__ Th)
{
  const int b = blockIdx.z;
  const int i0 = blockIdx.y * QBM, j0 = blockIdx.x * QBN;
  const long bofs = (long)b * UDIM * UDIM;
  const __bf16* A = Wth;
  const __bf16* B = G + bofs;
  __bf16* Out = Th + bofs;

  QGEMM_CORE(A, B)

#pragma unroll
  for (int mi = 0; mi < 2; ++mi)
#pragma unroll
    for (int ni = 0; ni < 4; ++ni)
#pragma unroll
      for (int v = 0; v < 4; ++v)
        Out[(size_t)(i0 + w*32 + mi*16 + q*4 + v)*UDIM + j0 + ni*16 + r]
            = (__bf16)acc[mi][ni][v];
}

// right_h: final Sigma_out (reads Sz in-place from out_sig).  grid (4, 2, 64).
__global__ __launch_bounds__(256) void right_h(
    const __bf16* __restrict__ Th, const __bf16* __restrict__ Wth,
    const float* __restrict__ S, const float* __restrict__ prev,
    const float* __restrict__ zb, const float* __restrict__ hb,
    const float* __restrict__ ghb,
    const float* __restrict__ wh_s, const float* __restrict__ uh_s,
    float* __restrict__ scal, float* __restrict__ out_sig)
{
  const int b = blockIdx.z;
  const int i0 = blockIdx.y * QBM, j0 = blockIdx.x * QBN;
  const long ob = (long)b * UDIM * UDIM;
  const __bf16* A = Th + ob;
  const __bf16* B = Wth;

  QGEMM_CORE(A, B)

  const float xx = scal[b];
  const float dscal = scal[192 + b] + scal[256 + b];  // gg + trG

#pragma unroll
  for (int mi = 0; mi < 2; ++mi) {
    const int ib = i0 + w*32 + mi*16 + q*4;
    const f32x4 g4 = *(const f32x4*)(ghb + b*UDIM + ib);
    const f32x4 p4 = *(const f32x4*)(prev + b*UDIM + ib);
    const f32x4 z4 = *(const f32x4*)(zb + b*UDIM + ib);
    const f32x4 h4 = *(const f32x4*)(hb + b*UDIM + ib);
#pragma unroll
    for (int ni = 0; ni < 4; ++ni) {
      const int j = j0 + ni*16 + r;
      const float gj = ghb[b*UDIM + j];
      const float pj = prev[b*UDIM + j];
      const float zj = zb[b*UDIM + j];
      const float hj = hb[b*UDIM + j];
#pragma unroll
      for (int v = 0; v < 4; ++v) {
        const int i = ib + v;
        float qv = acc[mi][ni][v];
        if (i == j)
          qv += dscal * softplusf(wh_s[i]) + xx * softplusf(uh_s[i]);
        const float Sg = qv * g4[v] * gj;
        const float s  = S[ob + (size_t)i*UDIM + j];
        const float sz = out_sig[ob + (size_t)i*UDIM + j];
        float val = s * (sz + z4[v]*zj)
                  + sz * (p4[v]-h4[v]) * (pj-hj)
                  + Sg * (sz + (1.f-z4[v])*(1.f-zj));
        if (!isfinite(val)) val = 0.f;
        if (i == j) val = fabsf(val);
        out_sig[ob + (size_t)i*UDIM + j] = val;
      }
    }
  }
}

// ---------------------------------------------------------------------------
extern "C" void kernel_launch(void* const* d_in, const int* in_sizes, int n_in,
                              void* d_out, int out_size, void* d_ws, size_t ws_size,
                              hipStream_t stream) {
  const float* x    = (const float*)d_in[0];
  const float* prev = (const float*)d_in[1];
  const float* S    = (const float*)d_in[2];
  const float* Uz   = (const float*)d_in[3];
  const float* uz_s = (const float*)d_in[4];
  const float* Wz   = (const float*)d_in[5];
  const float* wz_s = (const float*)d_in[6];
  const float* Ur   = (const float*)d_in[7];
  const float* ur_s = (const float*)d_in[8];
  const float* Wr   = (const float*)d_in[9];
  const float* wr_s = (const float*)d_in[10];
  const float* Uh   = (const float*)d_in[11];
  const float* uh_s = (const float*)d_in[12];
  const float* Wh   = (const float*)d_in[13];
  const float* wh_s = (const float*)d_in[14];

  float* out_mu  = (float*)d_out;
  float* out_sig = out_mu + BATCH*UDIM;

  float* ws   = (float*)d_ws;
  float* zb   = ws;
  float* rb   = zb  + BATCH*UDIM;
  float* gzb  = rb  + BATCH*UDIM;
  float* grb  = gzb + BATCH*UDIM;
  float* gin  = grb + BATCH*UDIM;
  float* hb   = gin + BATCH*UDIM;
  float* ghb  = hb  + BATCH*UDIM;
  float* scal = ghb + BATCH*UDIM;            // 512 floats
  __bf16* bws = (__bf16*)(ws + 7*BATCH*UDIM + 512);
  __bf16* Utz = bws;
  __bf16* Wtz = Utz + UDIM*UDIM;
  __bf16* Utr = Wtz + UDIM*UDIM;
  __bf16* Wtr = Utr + UDIM*UDIM;
  __bf16* Uth = Wtr + UDIM*UDIM;
  __bf16* Wth = Uth + UDIM*UDIM;
  const long US = (long)BATCH*UDIM*UDIM;
  __bf16* Sbf = Wth + UDIM*UDIM;             // [B,U,U] bf16
  __bf16* Tz  = Sbf + US;                    // [B,U,U] bf16 (reused as Th)
  __bf16* Tr  = Tz + US;
  __bf16* G   = Tr + US;
  __bf16* Th  = Tz;                          // reuse: right_zr done before left_h

  hipMemsetAsync(scal, 0, 512 * sizeof(float), stream);

  transpose6<<<dim3(4,4,6), 256, 0, stream>>>(Uz, Wz, Ur, Wr, Uh, Wh,
                                              Utz, Wtz, Utr, Wtr, Uth, Wth);
  sconv<<<dim3(BATCH,4), 256, 0, stream>>>(S, x, prev, Sbf, scal);
  gates_zr<<<dim3(4,2), 256, 0, stream>>>(x, prev, Utz, Wtz, Utr, Wtr,
                                          zb, rb, gzb, grb, gin, scal);
  gates_h<<<dim3(4), 256, 0, stream>>>(x, gin, Uth, Wth, prev, zb,
                                       hb, ghb, out_mu);

  left_zr<<<dim3(4,2,128), 256, 0, stream>>>(Wtz, Wtr, Sbf, Tz, Tr);
  right_zr<<<dim3(4,2,128), 256, 0, stream>>>(Tz, Tr, Wtz, Wtr, S, prev, rb,
      gzb, grb, wz_s, uz_s, wr_s, ur_s, scal, out_sig, G);
  left_h<<<dim3(4,2,64), 256, 0, stream>>>(Wth, G, Th);
  right_h<<<dim3(4,2,64), 256, 0, stream>>>(Th, Wth, S, prev, zb, hb, ghb,
      wh_s, uh_s, scal, out_sig);
}

// Round 5
// 191.066 us; speedup vs baseline: 1.8218x; 1.1834x over previous
//
#include <hip/hip_runtime.h>
#include <math.h>

#define UDIM 256
#define BATCH 64
#define MATN 65536  // 256*256

typedef __bf16 bf16x8 __attribute__((ext_vector_type(8)));
typedef float  f32x4  __attribute__((ext_vector_type(4)));

__device__ __forceinline__ float softplusf(float x) { return log1pf(expf(x)); }
__device__ __forceinline__ float sigmoidf_(float x) { return 1.f/(1.f+expf(-x)); }

// ---------------------------------------------------------------------------
// Fragment-direct layout for a 256x256 bf16 matrix M[row][k]:
// chunk(rt,kt) = rows rt*16..+15, k kt*32..+31; lane = (row&15) | ((k>>3)&3)<<4,
// each lane holds 8 contiguous k (16B). Serves both A and B MFMA operands
// (identical lane mapping, verified by round-3/4 passing kernels).
// ---------------------------------------------------------------------------
__device__ __forceinline__ bf16x8 frag_load(const __bf16* base, int rt, int kt, int lane) {
  return *(const bf16x8*)(base + (((size_t)(rt*8 + kt))*64 + lane)*8);
}

// Bounce 16 fp32 values (C-layout, idx = ni*4+v) through LDS into fragment-
// direct global layout. Tile covers rows by*64..+63 (i), k bx*64..+63.
__device__ __forceinline__ void bounce_emit16(
    const float* vals, __bf16 (*tile)[72], __bf16* dst, size_t sb,
    int bx, int by, int t, int w, int r, int q)
{
  __syncthreads();
#pragma unroll
  for (int ni = 0; ni < 4; ++ni)
#pragma unroll
    for (int v = 0; v < 4; ++v)
      tile[w*16 + q*4 + v][ni*16 + r] = (__bf16)vals[ni*4 + v];
  __syncthreads();
#pragma unroll
  for (int ss = 0; ss < 2; ++ss) {
    const int s = t + ss*256;
    const int rt_l = s >> 7, kt_l = (s >> 6) & 1, lane = s & 63;
    const uint4 vv = *(const uint4*)&tile[rt_l*16 + (lane & 15)][kt_l*32 + (lane >> 4)*8];
    *(uint4*)(dst + sb + (((size_t)((by*4 + rt_l)*8 + bx*2 + kt_l))*64 + lane)*8) = vv;
  }
}

// ---------------------------------------------------------------------------
// prep6: z<6 -> fragment-direct bf16 transpose of the 6 weight matrices.
//        z==6 -> scalar reductions xx, pp, trS into scal.
// grid (4,4,7), 256 threads.
// scal: xx[0..63], pp[64..127], trS[128..191], gg[192..255], trG[256..319]
// ---------------------------------------------------------------------------
__global__ __launch_bounds__(256) void prep6(
    const float* __restrict__ Uz, const float* __restrict__ Wz,
    const float* __restrict__ Ur, const float* __restrict__ Wr,
    const float* __restrict__ Uh, const float* __restrict__ Wh,
    __bf16* __restrict__ Fu_z, __bf16* __restrict__ Fw_z,
    __bf16* __restrict__ Fu_r, __bf16* __restrict__ Fw_r,
    __bf16* __restrict__ Fu_h, __bf16* __restrict__ Fw_h,
    const float* __restrict__ S, const float* __restrict__ x,
    const float* __restrict__ prev, float* __restrict__ scal)
{
  const int t = threadIdx.x;
  if (blockIdx.z == 6) {
    const int blk = blockIdx.y*4 + blockIdx.x;      // 0..15
    const int b = blk*4 + (t >> 6), l = t & 63;
    const float4 xv = *(const float4*)(x + b*UDIM + l*4);
    float s0 = xv.x*xv.x + xv.y*xv.y + xv.z*xv.z + xv.w*xv.w;
    const float4 pv = *(const float4*)(prev + b*UDIM + l*4);
    float s1 = pv.x*pv.x + pv.y*pv.y + pv.z*pv.z + pv.w*pv.w;
    float s2 = 0.f;
#pragma unroll
    for (int e = 0; e < 4; ++e)
      s2 += S[(size_t)b*MATN + (size_t)(l*4 + e)*257];
    for (int off = 32; off; off >>= 1) {
      s0 += __shfl_down(s0, off);
      s1 += __shfl_down(s1, off);
      s2 += __shfl_down(s2, off);
    }
    if (l == 0) {
      atomicAdd(&scal[b], s0);
      atomicAdd(&scal[64 + b], s1);
      atomicAdd(&scal[128 + b], s2);
    }
    return;
  }
  const float* W; __bf16* F;
  switch (blockIdx.z) {
    case 0: W = Uz; F = Fu_z; break;  case 1: W = Wz; F = Fw_z; break;
    case 2: W = Ur; F = Fu_r; break;  case 3: W = Wr; F = Fw_r; break;
    case 4: W = Uh; F = Fu_h; break;  default: W = Wh; F = Fw_h; break;
  }
  const int k0 = blockIdx.y*64, n0 = blockIdx.x*64;
  __shared__ float tile[64][65];
  const int tx = t & 15, ty = t >> 4;
#pragma unroll
  for (int rr = 0; rr < 4; ++rr) {
    const int row = ty*4 + rr;
    const float4 f = *(const float4*)(W + (size_t)(k0 + row)*UDIM + n0 + tx*4);
    tile[row][tx*4+0] = f.x; tile[row][tx*4+1] = f.y;
    tile[row][tx*4+2] = f.z; tile[row][tx*4+3] = f.w;
  }
  __syncthreads();
#pragma unroll
  for (int ss = 0; ss < 2; ++ss) {
    const int s = t + ss*256;
    const int rt_l = s >> 7, kt_l = (s >> 6) & 1, lane = s & 63;
    const int nl = rt_l*16 + (lane & 15), kb = kt_l*32 + (lane >> 4)*8;
    __align__(16) __bf16 tmp[8];
#pragma unroll
    for (int e = 0; e < 8; ++e) tmp[e] = (__bf16)tile[kb + e][nl];
    *(uint4*)(F + (((size_t)((((n0 >> 4) + rt_l)*8) + (k0 >> 5) + kt_l))*64 + lane)*8)
        = *(const uint4*)tmp;
  }
}

// ---------------------------------------------------------------------------
// gates_zr: az/ar = x@U + prev@W via MFMA straight from global.
// grid (4 j-tiles, 2 gates).  B operands from fragment-direct weights.
// ---------------------------------------------------------------------------
__global__ __launch_bounds__(256) void gates_zr(
    const float* __restrict__ x, const float* __restrict__ prev,
    const __bf16* __restrict__ Fu_z, const __bf16* __restrict__ Fw_z,
    const __bf16* __restrict__ Fu_r, const __bf16* __restrict__ Fw_r,
    float* __restrict__ zb, float* __restrict__ rb,
    float* __restrict__ gzb, float* __restrict__ grb,
    float* __restrict__ gin, float* __restrict__ scal)
{
  const int jt = blockIdx.x;               // j-tile of 64 -> rt base jt*4
  const int gate = blockIdx.y;
  const __bf16* FU = gate ? Fu_r : Fu_z;
  const __bf16* FW = gate ? Fw_r : Fw_z;
  const int t = threadIdx.x, w = t >> 6, l = t & 63, r = l & 15, q = l >> 4;
  const int mrow = w*16 + r;

  f32x4 acc[4] = {};
#pragma unroll
  for (int ks = 0; ks < 16; ++ks) {
    const int k0 = ks*32;
    const float* asrc; const __bf16* B; int kk;
    if (k0 < 256) { asrc = x    + (size_t)mrow*UDIM + k0         + q*8; B = FU; kk = k0; }
    else          { asrc = prev + (size_t)mrow*UDIM + (k0 - 256) + q*8; B = FW; kk = k0 - 256; }
    const float4 f0 = *(const float4*)asrc;
    const float4 f1 = *(const float4*)(asrc + 4);
    bf16x8 af;
    af[0]=(__bf16)f0.x; af[1]=(__bf16)f0.y; af[2]=(__bf16)f0.z; af[3]=(__bf16)f0.w;
    af[4]=(__bf16)f1.x; af[5]=(__bf16)f1.y; af[6]=(__bf16)f1.z; af[7]=(__bf16)f1.w;
#pragma unroll
    for (int ni = 0; ni < 4; ++ni) {
      const bf16x8 bv = frag_load(B, jt*4 + ni, kk >> 5, l);
      acc[ni] = __builtin_amdgcn_mfma_f32_16x16x32_bf16(af, bv, acc[ni], 0, 0, 0);
    }
  }

  if (gate == 0) {
#pragma unroll
    for (int ni = 0; ni < 4; ++ni) {
      const int n = jt*64 + ni*16 + r;
#pragma unroll
      for (int v = 0; v < 4; ++v) {
        const int m = w*16 + q*4 + v;
        const float zv = sigmoidf_(acc[ni][v]);
        zb[m*UDIM + n]  = zv;
        gzb[m*UDIM + n] = zv * (1.f - zv);
      }
    }
  } else {
    float ggp[4] = {0.f, 0.f, 0.f, 0.f};
#pragma unroll
    for (int ni = 0; ni < 4; ++ni) {
      const int n = jt*64 + ni*16 + r;
#pragma unroll
      for (int v = 0; v < 4; ++v) {
        const int m = w*16 + q*4 + v;
        const float rv = sigmoidf_(acc[ni][v]);
        const float pv = prev[m*UDIM + n];
        const float g  = pv * rv;
        rb[m*UDIM + n]  = rv;
        grb[m*UDIM + n] = rv * (1.f - rv);
        gin[m*UDIM + n] = g;
        ggp[v] += g * g;
      }
    }
#pragma unroll
    for (int s = 1; s < 16; s <<= 1)
#pragma unroll
      for (int v = 0; v < 4; ++v) ggp[v] += __shfl_xor(ggp[v], s);
    if (r == 0)
#pragma unroll
      for (int v = 0; v < 4; ++v)
        atomicAdd(&scal[192 + w*16 + q*4 + v], ggp[v]);
  }
}

// ---------------------------------------------------------------------------
// gates_h: ah = x@Uh + gin@Wh -> h, gh, mu_out.  grid (4).
// ---------------------------------------------------------------------------
__global__ __launch_bounds__(256) void gates_h(
    const float* __restrict__ x, const float* __restrict__ gin,
    const __bf16* __restrict__ Fu_h, const __bf16* __restrict__ Fw_h,
    const float* __restrict__ prev, const float* __restrict__ zb,
    float* __restrict__ hb, float* __restrict__ ghb, float* __restrict__ mu_out)
{
  const int jt = blockIdx.x;
  const int t = threadIdx.x, w = t >> 6, l = t & 63, r = l & 15, q = l >> 4;
  const int mrow = w*16 + r;

  f32x4 acc[4] = {};
#pragma unroll
  for (int ks = 0; ks < 16; ++ks) {
    const int k0 = ks*32;
    const float* asrc; const __bf16* B; int kk;
    if (k0 < 256) { asrc = x   + (size_t)mrow*UDIM + k0         + q*8; B = Fu_h; kk = k0; }
    else          { asrc = gin + (size_t)mrow*UDIM + (k0 - 256) + q*8; B = Fw_h; kk = k0 - 256; }
    const float4 f0 = *(const float4*)asrc;
    const float4 f1 = *(const float4*)(asrc + 4);
    bf16x8 af;
    af[0]=(__bf16)f0.x; af[1]=(__bf16)f0.y; af[2]=(__bf16)f0.z; af[3]=(__bf16)f0.w;
    af[4]=(__bf16)f1.x; af[5]=(__bf16)f1.y; af[6]=(__bf16)f1.z; af[7]=(__bf16)f1.w;
#pragma unroll
    for (int ni = 0; ni < 4; ++ni) {
      const bf16x8 bv = frag_load(B, jt*4 + ni, kk >> 5, l);
      acc[ni] = __builtin_amdgcn_mfma_f32_16x16x32_bf16(af, bv, acc[ni], 0, 0, 0);
    }
  }

#pragma unroll
  for (int ni = 0; ni < 4; ++ni) {
    const int n = jt*64 + ni*16 + r;
#pragma unroll
    for (int v = 0; v < 4; ++v) {
      const int m = w*16 + q*4 + v;
      const float hv = tanhf(acc[ni][v]);
      const float zv = zb[m*UDIM + n];
      hb[m*UDIM + n]  = hv;
      ghb[m*UDIM + n] = 1.f - hv*hv;
      mu_out[m*UDIM + n] = zv * prev[m*UDIM + n] + (1.f - zv) * hv;
    }
  }
}

// ---------------------------------------------------------------------------
// left_zr: Tz = Wtz @ S, Tr = Wtr @ S (both gates, S staged once).
// grid (4 c-tiles, 4 i-tiles, 64 batch).  Outputs fragment-direct.
// ---------------------------------------------------------------------------
__global__ __launch_bounds__(256) void left_zr(
    const __bf16* __restrict__ Fw_z, const __bf16* __restrict__ Fw_r,
    const float* __restrict__ S,
    __bf16* __restrict__ Tz, __bf16* __restrict__ Tr)
{
  const int bx = blockIdx.x, by = blockIdx.y, b = blockIdx.z;
  const size_t sb = (size_t)b * MATN;
  __shared__ __align__(16) __bf16 smem[64*72];
  __bf16 (*Bs)[40]   = (__bf16(*)[40])smem;
  __bf16 (*tile)[72] = (__bf16(*)[72])smem;
  const int t = threadIdx.x, w = t >> 6, l = t & 63, r = l & 15, q = l >> 4;
  const int brow = t >> 2, bcq = (t & 3)*8;
  const float* bsrc0 = S + sb + (size_t)(bx*64 + brow)*UDIM + bcq;

  __align__(16) __bf16 breg[8];
  {
    const float4 f0 = *(const float4*)bsrc0;
    const float4 f1 = *(const float4*)(bsrc0 + 4);
    breg[0]=(__bf16)f0.x; breg[1]=(__bf16)f0.y; breg[2]=(__bf16)f0.z; breg[3]=(__bf16)f0.w;
    breg[4]=(__bf16)f1.x; breg[5]=(__bf16)f1.y; breg[6]=(__bf16)f1.z; breg[7]=(__bf16)f1.w;
  }
  f32x4 az[4] = {}, ar[4] = {};
  for (int k0 = 0; k0 < 256; k0 += 32) {
    __syncthreads();
    *(uint4*)&Bs[brow][bcq] = *(const uint4*)breg;
    __syncthreads();
    if (k0 < 224) {
      const float4 f0 = *(const float4*)(bsrc0 + k0 + 32);
      const float4 f1 = *(const float4*)(bsrc0 + k0 + 36);
      breg[0]=(__bf16)f0.x; breg[1]=(__bf16)f0.y; breg[2]=(__bf16)f0.z; breg[3]=(__bf16)f0.w;
      breg[4]=(__bf16)f1.x; breg[5]=(__bf16)f1.y; breg[6]=(__bf16)f1.z; breg[7]=(__bf16)f1.w;
    }
    const int kt = k0 >> 5;
    const bf16x8 afz = frag_load(Fw_z, by*4 + w, kt, l);
    const bf16x8 afr = frag_load(Fw_r, by*4 + w, kt, l);
    bf16x8 bv[4];
#pragma unroll
    for (int ni = 0; ni < 4; ++ni) bv[ni] = *(const bf16x8*)&Bs[ni*16 + r][q*8];
#pragma unroll
    for (int ni = 0; ni < 4; ++ni) {
      az[ni] = __builtin_amdgcn_mfma_f32_16x16x32_bf16(afz, bv[ni], az[ni], 0, 0, 0);
      ar[ni] = __builtin_amdgcn_mfma_f32_16x16x32_bf16(afr, bv[ni], ar[ni], 0, 0, 0);
    }
  }
  float vals[16];
#pragma unroll
  for (int ni = 0; ni < 4; ++ni)
#pragma unroll
    for (int v = 0; v < 4; ++v) vals[ni*4 + v] = az[ni][v];
  bounce_emit16(vals, tile, Tz, sb, bx, by, t, w, r, q);
#pragma unroll
  for (int ni = 0; ni < 4; ++ni)
#pragma unroll
    for (int v = 0; v < 4; ++v) vals[ni*4 + v] = ar[ni][v];
  bounce_emit16(vals, tile, Tr, sb, bx, by, t, w, r, q);
}

// ---------------------------------------------------------------------------
// right_zr: Q = T_g @ W_g + diag.  No LDS in K-loop (all fragment-direct).
// gate 0 -> Sigma_out_z (bf16, C-linear) into Szb; gate 1 -> sigma_g -> G
// (fragment-direct) + trG atomics.  grid (4 j, 4 i, 128 = gate*64+b).
// ---------------------------------------------------------------------------
__global__ __launch_bounds__(256) void right_zr(
    const __bf16* __restrict__ Tz, const __bf16* __restrict__ Tr,
    const __bf16* __restrict__ Fw_z, const __bf16* __restrict__ Fw_r,
    const float* __restrict__ S, const float* __restrict__ prev,
    const float* __restrict__ rb, const float* __restrict__ gzb,
    const float* __restrict__ grb,
    const float* __restrict__ wz_s, const float* __restrict__ uz_s,
    const float* __restrict__ wr_s, const float* __restrict__ ur_s,
    float* __restrict__ scal, __bf16* __restrict__ Szb, __bf16* __restrict__ G)
{
  const int bx = blockIdx.x, by = blockIdx.y;
  const int gate = blockIdx.z >> 6, b = blockIdx.z & 63;
  const size_t sb = (size_t)b * MATN;
  const __bf16* A  = (gate ? Tr : Tz) + sb;
  const __bf16* BW = gate ? Fw_r : Fw_z;
  __shared__ __align__(16) __bf16 tile[64][72];
  const int t = threadIdx.x, w = t >> 6, l = t & 63, r = l & 15, q = l >> 4;

  f32x4 acc[4] = {};
#pragma unroll
  for (int kt = 0; kt < 8; ++kt) {
    const bf16x8 af = frag_load(A, by*4 + w, kt, l);
#pragma unroll
    for (int ni = 0; ni < 4; ++ni) {
      const bf16x8 bv = frag_load(BW, bx*4 + ni, kt, l);
      acc[ni] = __builtin_amdgcn_mfma_f32_16x16x32_bf16(af, bv, acc[ni], 0, 0, 0);
    }
  }

  const float xx = scal[b];
  const float dscal = scal[64 + b] + scal[128 + b];   // pp + trS
  const float* gg_ = gate ? grb : gzb;
  const float* ws_ = gate ? wr_s : wz_s;
  const float* us_ = gate ? ur_s : uz_s;
  const int ib = by*64 + w*16 + q*4;
  const f32x4 g4 = *(const f32x4*)(gg_ + b*UDIM + ib);
  float vals[16];

  if (!gate) {
#pragma unroll
    for (int ni = 0; ni < 4; ++ni) {
      const int j = bx*64 + ni*16 + r;
      const float gj = gg_[b*UDIM + j];
#pragma unroll
      for (int v = 0; v < 4; ++v) {
        const int i = ib + v;
        float qv = acc[ni][v];
        if (i == j) qv += dscal*softplusf(ws_[i]) + xx*softplusf(us_[i]);
        vals[ni*4 + v] = qv * g4[v] * gj;
      }
    }
    __align__(16) __bf16 o16[16];
#pragma unroll
    for (int e = 0; e < 16; ++e) o16[e] = (__bf16)vals[e];
    __bf16* dst = Szb + ((size_t)(b*16 + by*4 + bx))*4096 + t*16;
    *(uint4*)dst       = *(const uint4*)&o16[0];
    *(uint4*)(dst + 8) = *(const uint4*)&o16[8];
  } else {
    const f32x4 p4 = *(const f32x4*)(prev + b*UDIM + ib);
    const f32x4 r4 = *(const f32x4*)(rb + b*UDIM + ib);
    float trg = 0.f;
#pragma unroll
    for (int ni = 0; ni < 4; ++ni) {
      const int j = bx*64 + ni*16 + r;
      const float gj = gg_[b*UDIM + j];
      const float pj = prev[b*UDIM + j], rj = rb[b*UDIM + j];
#pragma unroll
      for (int v = 0; v < 4; ++v) {
        const int i = ib + v;
        float qv = acc[ni][v];
        if (i == j) qv += dscal*softplusf(ws_[i]) + xx*softplusf(us_[i]);
        const float Sg = qv * g4[v] * gj;
        const float s = S[sb + (size_t)i*UDIM + j];
        const float go = Sg*(s + p4[v]*pj) + r4[v]*rj*s;
        vals[ni*4 + v] = go;
        if (i == j) trg += go;
      }
    }
    if (trg != 0.f) atomicAdd(&scal[256 + b], trg);
    bounce_emit16(vals, tile, G, sb, bx, by, t, w, r, q);
  }
}

// ---------------------------------------------------------------------------
// left_h: Th = Wth @ G.  Both operands fragment-direct -> no LDS K-loop.
// grid (4 c, 4 i, 64).  Output fragment-direct.
// ---------------------------------------------------------------------------
__global__ __launch_bounds__(256) void left_h(
    const __bf16* __restrict__ Fw_h, const __bf16* __restrict__ G,
    __bf16* __restrict__ Th)
{
  const int bx = blockIdx.x, by = blockIdx.y, b = blockIdx.z;
  const size_t sb = (size_t)b * MATN;
  __shared__ __align__(16) __bf16 tile[64][72];
  const int t = threadIdx.x, w = t >> 6, l = t & 63, r = l & 15, q = l >> 4;
  const __bf16* Gb = G + sb;

  f32x4 acc[4] = {};
#pragma unroll
  for (int kt = 0; kt < 8; ++kt) {
    const bf16x8 af = frag_load(Fw_h, by*4 + w, kt, l);
#pragma unroll
    for (int ni = 0; ni < 4; ++ni) {
      const bf16x8 bv = frag_load(Gb, bx*4 + ni, kt, l);
      acc[ni] = __builtin_amdgcn_mfma_f32_16x16x32_bf16(af, bv, acc[ni], 0, 0, 0);
    }
  }
  float vals[16];
#pragma unroll
  for (int ni = 0; ni < 4; ++ni)
#pragma unroll
    for (int v = 0; v < 4; ++v) vals[ni*4 + v] = acc[ni][v];
  bounce_emit16(vals, tile, Th, sb, bx, by, t, w, r, q);
}

// ---------------------------------------------------------------------------
// right_h: final Sigma_out.  No-LDS K-loop; epilogue reads S (fp32), Szb
// (bf16 C-linear), writes d_out fp32.  grid (4 j, 4 i, 64).
// ---------------------------------------------------------------------------
__global__ __launch_bounds__(256) void right_h(
    const __bf16* __restrict__ Th, const __bf16* __restrict__ Fw_h,
    const float* __restrict__ S, const __bf16* __restrict__ Szb,
    const float* __restrict__ prev, const float* __restrict__ zb,
    const float* __restrict__ hb, const float* __restrict__ ghb,
    const float* __restrict__ wh_s, const float* __restrict__ uh_s,
    const float* __restrict__ scal, float* __restrict__ out_sig)
{
  const int bx = blockIdx.x, by = blockIdx.y, b = blockIdx.z;
  const size_t sb = (size_t)b * MATN;
  const __bf16* A = Th + sb;
  const int t = threadIdx.x, w = t >> 6, l = t & 63, r = l & 15, q = l >> 4;

  f32x4 acc[4] = {};
#pragma unroll
  for (int kt = 0; kt < 8; ++kt) {
    const bf16x8 af = frag_load(A, by*4 + w, kt, l);
#pragma unroll
    for (int ni = 0; ni < 4; ++ni) {
      const bf16x8 bv = frag_load(Fw_h, bx*4 + ni, kt, l);
      acc[ni] = __builtin_amdgcn_mfma_f32_16x16x32_bf16(af, bv, acc[ni], 0, 0, 0);
    }
  }

  const float xx = scal[b];
  const float dscal = scal[192 + b] + scal[256 + b];  // gg + trG
  const int ib = by*64 + w*16 + q*4;
  const f32x4 g4 = *(const f32x4*)(ghb + b*UDIM + ib);
  const f32x4 p4 = *(const f32x4*)(prev + b*UDIM + ib);
  const f32x4 z4 = *(const f32x4*)(zb + b*UDIM + ib);
  const f32x4 h4 = *(const f32x4*)(hb + b*UDIM + ib);

  const __bf16* szp = Szb + ((size_t)(b*16 + by*4 + bx))*4096 + t*16;
  __align__(16) __bf16 sz16[16];
  *(uint4*)&sz16[0] = *(const uint4*)szp;
  *(uint4*)&sz16[8] = *(const uint4*)(szp + 8);

#pragma unroll
  for (int ni = 0; ni < 4; ++ni) {
    const int j = bx*64 + ni*16 + r;
    const float gj = ghb[b*UDIM + j];
    const float pj = prev[b*UDIM + j];
    const float zj = zb[b*UDIM + j];
    const float hj = hb[b*UDIM + j];
#pragma unroll
    for (int v = 0; v < 4; ++v) {
      const int i = ib + v;
      float qv = acc[ni][v];
      if (i == j) qv += dscal*softplusf(wh_s[i]) + xx*softplusf(uh_s[i]);
      const float Sg = qv * g4[v] * gj;
      const float s  = S[sb + (size_t)i*UDIM + j];
      const float sz = (float)sz16[ni*4 + v];
      float val = s*(sz + z4[v]*zj)
                + sz*(p4[v] - h4[v])*(pj - hj)
                + Sg*(sz + (1.f - z4[v])*(1.f - zj));
      if (!isfinite(val)) val = 0.f;
      if (i == j) val = fabsf(val);
      out_sig[sb + (size_t)i*UDIM + j] = val;
    }
  }
}

// ---------------------------------------------------------------------------
extern "C" void kernel_launch(void* const* d_in, const int* in_sizes, int n_in,
                              void* d_out, int out_size, void* d_ws, size_t ws_size,
                              hipStream_t stream) {
  const float* x    = (const float*)d_in[0];
  const float* prev = (const float*)d_in[1];
  const float* S    = (const float*)d_in[2];
  const float* Uz   = (const float*)d_in[3];
  const float* uz_s = (const float*)d_in[4];
  const float* Wz   = (const float*)d_in[5];
  const float* wz_s = (const float*)d_in[6];
  const float* Ur   = (const float*)d_in[7];
  const float* ur_s = (const float*)d_in[8];
  const float* Wr   = (const float*)d_in[9];
  const float* wr_s = (const float*)d_in[10];
  const float* Uh   = (const float*)d_in[11];
  const float* uh_s = (const float*)d_in[12];
  const float* Wh   = (const float*)d_in[13];
  const float* wh_s = (const float*)d_in[14];

  float* out_mu  = (float*)d_out;
  float* out_sig = out_mu + BATCH*UDIM;

  float* ws   = (float*)d_ws;
  float* zb   = ws;
  float* rb   = zb  + BATCH*UDIM;
  float* gzb  = rb  + BATCH*UDIM;
  float* grb  = gzb + BATCH*UDIM;
  float* gin  = grb + BATCH*UDIM;
  float* hb   = gin + BATCH*UDIM;
  float* ghb  = hb  + BATCH*UDIM;
  float* scal = ghb + BATCH*UDIM;            // 512 floats
  __bf16* bws  = (__bf16*)(ws + 7*BATCH*UDIM + 512);
  __bf16* Fu_z = bws;
  __bf16* Fw_z = Fu_z + MATN;
  __bf16* Fu_r = Fw_z + MATN;
  __bf16* Fw_r = Fu_r + MATN;
  __bf16* Fu_h = Fw_r + MATN;
  __bf16* Fw_h = Fu_h + MATN;
  const size_t BIG = (size_t)BATCH * MATN;
  __bf16* Tz  = Fw_h + MATN;
  __bf16* Tr  = Tz + BIG;
  __bf16* G   = Tr + BIG;
  __bf16* Szb = G + BIG;
  __bf16* Th  = Tz;   // reuse: Tz consumed by right_zr before left_h writes

  hipMemsetAsync(scal, 0, 512*sizeof(float), stream);

  prep6<<<dim3(4,4,7), 256, 0, stream>>>(Uz, Wz, Ur, Wr, Uh, Wh,
      Fu_z, Fw_z, Fu_r, Fw_r, Fu_h, Fw_h, S, x, prev, scal);
  gates_zr<<<dim3(4,2), 256, 0, stream>>>(x, prev, Fu_z, Fw_z, Fu_r, Fw_r,
      zb, rb, gzb, grb, gin, scal);
  gates_h<<<dim3(4), 256, 0, stream>>>(x, gin, Fu_h, Fw_h, prev, zb,
      hb, ghb, out_mu);

  left_zr<<<dim3(4,4,64), 256, 0, stream>>>(Fw_z, Fw_r, S, Tz, Tr);
  right_zr<<<dim3(4,4,128), 256, 0, stream>>>(Tz, Tr, Fw_z, Fw_r, S, prev,
      rb, gzb, grb, wz_s, uz_s, wr_s, ur_s, scal, Szb, G);
  left_h<<<dim3(4,4,64), 256, 0, stream>>>(Fw_h, G, Th);
  right_h<<<dim3(4,4,64), 256, 0, stream>>>(Th, Fw_h, S, Szb, prev, zb,
      hb, ghb, wh_s, uh_s, scal, out_sig);
}